// Round 1
// baseline (4626.848 us; speedup 1.0000x reference)
//
#include <hip/hip_runtime.h>
#include <hip/hip_bf16.h>

// Hierarchical BiGRU (word-level T=50 over 2560 sentences, sentence-level T=10
// over 256 docs) + masked avg pools + linear heads + sigmoid.
// Round 0: all-fp32 compute baseline. gx pre-activations stored bf16 in ws
// (154 MB buffer reused for fwd/bwd word dirs and sentence level).
//
// ws layout (bytes):
//   [0, 153.6MB)      gx buffer  (128000 x 600 bf16)   reused 4x
//   +  s_in  2560x400 f32 (pooled word outputs = sentence inputs)
//   +  d_pool 256x400 f32 (pooled sentence outputs)
//   +  sent_lens 2560 i32
//   +  wT[4]: 200x600 f32 transposed W_hh for each GRU direction
// total ~160 MB.

typedef __hip_bfloat16 bf16;

#define HDIM 200
#define G3   600
#define NS   2560
#define TW   50
#define ND   256
#define DTR  10

__device__ __forceinline__ float sigf(float x) { return 1.f / (1.f + __expf(-x)); }
__device__ __forceinline__ float tanh_fast(float x) {
    float e = __expf(2.f * x);
    return (e - 1.f) / (e + 1.f);
}

// ---------------- transpose W_hh (600x200) -> wT (200x600) ----------------
__global__ void transpose_hh(const float* __restrict__ w, float* __restrict__ wT) {
    int i = blockIdx.x * 256 + threadIdx.x;
    if (i < G3 * HDIM) {
        int g = i / HDIM, k = i % HDIM;
        wT[k * G3 + g] = w[i];
    }
}

// ---------------- sentence lengths: count of nonzero tokens ----------------
__global__ void lens_kernel(const int* __restrict__ x, int* __restrict__ sl) {
    int s = blockIdx.x * 256 + threadIdx.x;
    if (s < NS) {
        int c = 0;
        for (int t = 0; t < TW; ++t) c += (x[s * TW + t] != 0) ? 1 : 0;
        sl[s] = c;
    }
}

// ---------------- GEMM: C[M][600] = gatherA[M][K] * W[600][K]^T + bias -----
// A row = A + tok*K, tok = idx ? idx[row] : row. C stored bf16.
// 64x64 tile, BK=16, 256 threads, 4x4 register tile.
__global__ __launch_bounds__(256) void gemm_bias_bf16(
    const float* __restrict__ A, const int* __restrict__ idx,
    const float* __restrict__ W, const float* __restrict__ bias,
    bf16* __restrict__ C, int M, int K)
{
    __shared__ float As[16][68];   // [k][m], pad 68 -> 16B-aligned rows, no conflicts
    __shared__ float Bs[16][68];   // [k][n]
    __shared__ int toks[64];

    const int tid = threadIdx.x;
    const int r0 = blockIdx.x * 64;
    const int g0 = blockIdx.y * 64;
    if (tid < 64) {
        int r = r0 + tid;
        toks[tid] = idx ? idx[r] : r;
    }
    const int kk = tid & 15;   // k within tile
    const int rq = tid >> 4;   // 0..15 row quad
    const int tx = tid & 15;   // output col group
    const int ty = tid >> 4;   // output row group
    float c[4][4] = {};
    __syncthreads();

    for (int k0 = 0; k0 < K; k0 += 16) {
        const bool kv = (k0 + kk) < K;
#pragma unroll
        for (int p = 0; p < 4; ++p) {
            int r = rq * 4 + p;            // 0..63
            float av = 0.f;
            if (kv) av = A[(size_t)toks[r] * K + k0 + kk];
            As[kk][r] = av;
            int gg = g0 + r;
            float wv = 0.f;
            if (kv && gg < G3) wv = W[(size_t)gg * K + k0 + kk];
            Bs[kk][r] = wv;
        }
        __syncthreads();
#pragma unroll
        for (int kq = 0; kq < 16; ++kq) {
            float4 a = *(const float4*)&As[kq][ty * 4];
            float4 b = *(const float4*)&Bs[kq][tx * 4];
            float av[4] = {a.x, a.y, a.z, a.w};
            float bv[4] = {b.x, b.y, b.z, b.w};
#pragma unroll
            for (int i = 0; i < 4; ++i)
#pragma unroll
                for (int j = 0; j < 4; ++j)
                    c[i][j] += av[i] * bv[j];
        }
        __syncthreads();
    }

#pragma unroll
    for (int i = 0; i < 4; ++i) {
        int r = r0 + ty * 4 + i;           // always < M (M % 64 == 0)
#pragma unroll
        for (int j = 0; j < 4; ++j) {
            int gg = g0 + tx * 4 + j;
            if (gg < G3) {
                float v = c[i][j] + bias[gg];
                C[(size_t)r * G3 + gg] = __float2bfloat16(v);
            }
        }
    }
}

// ---------------- GRU recurrence + online masked avg-pool ----------------
// One block = 10 batch rows for all T steps. 320 threads:
//   tids 0..299: gate columns g = tid and tid+300 (gh = h @ W_hh^T + b_hh)
//   tids 0..199: gate combine + h update + pool accumulate (unit i = tid)
// h kept transposed in LDS: hT[k*12 + r] (stride 12 floats = 48B, 16B-aligned
// for float4 broadcast reads).
__global__ __launch_bounds__(320) void gru_kernel(
    const bf16* __restrict__ gx, const float* __restrict__ wT,
    const float* __restrict__ bh, const int* __restrict__ lens,
    float* __restrict__ pool, int nrows, int T, int dirOff, int rev)
{
    __shared__ float hT[HDIM * 12];    // [k][r], r<10, pad 12
    __shared__ float ghs[10 * G3];     // [r][g]
    __shared__ int slen[10];

    const int tid = threadIdx.x;
    const int row0 = blockIdx.x * 10;

    for (int i = tid; i < HDIM * 12; i += 320) hT[i] = 0.f;
    if (tid < 10) slen[tid] = (row0 + tid < nrows) ? lens[row0 + tid] : 0;
    float pacc[10];
#pragma unroll
    for (int r = 0; r < 10; ++r) pacc[r] = 0.f;

    const int g0i = tid;
    const int g1i = tid + 300;
    const bool gact = (tid < 300);
    float b0 = 0.f, b1 = 0.f;
    if (gact) { b0 = bh[g0i]; b1 = bh[g1i]; }
    __syncthreads();

    for (int ts = 0; ts < T; ++ts) {
        const int t = rev ? (T - 1 - ts) : ts;

        // prefetch this step's gx into regs (hidden under the k-loop)
        float xrv[10], xzv[10], xnv[10];
        if (tid < HDIM) {
#pragma unroll
            for (int r = 0; r < 10; ++r) {
                if (row0 + r < nrows) {
                    const bf16* gp = gx + ((size_t)(row0 + r) * T + t) * G3;
                    xrv[r] = __bfloat162float(gp[tid]);
                    xzv[r] = __bfloat162float(gp[HDIM + tid]);
                    xnv[r] = __bfloat162float(gp[2 * HDIM + tid]);
                } else { xrv[r] = 0.f; xzv[r] = 0.f; xnv[r] = 0.f; }
            }
        }

        if (gact) {
            float a0[10], a1[10];
#pragma unroll
            for (int r = 0; r < 10; ++r) { a0[r] = 0.f; a1[r] = 0.f; }
#pragma unroll 2
            for (int k = 0; k < HDIM; ++k) {
                float w0 = wT[k * G3 + g0i];
                float w1 = wT[k * G3 + g1i];
                const float* hk = &hT[k * 12];
                float4 hA = *(const float4*)(hk);
                float4 hB = *(const float4*)(hk + 4);
                float2 hC = *(const float2*)(hk + 8);
                a0[0] += hA.x * w0;  a1[0] += hA.x * w1;
                a0[1] += hA.y * w0;  a1[1] += hA.y * w1;
                a0[2] += hA.z * w0;  a1[2] += hA.z * w1;
                a0[3] += hA.w * w0;  a1[3] += hA.w * w1;
                a0[4] += hB.x * w0;  a1[4] += hB.x * w1;
                a0[5] += hB.y * w0;  a1[5] += hB.y * w1;
                a0[6] += hB.z * w0;  a1[6] += hB.z * w1;
                a0[7] += hB.w * w0;  a1[7] += hB.w * w1;
                a0[8] += hC.x * w0;  a1[8] += hC.x * w1;
                a0[9] += hC.y * w0;  a1[9] += hC.y * w1;
            }
#pragma unroll
            for (int r = 0; r < 10; ++r) {
                ghs[r * G3 + g0i] = a0[r] + b0;
                ghs[r * G3 + g1i] = a1[r] + b1;
            }
        }
        __syncthreads();

        if (tid < HDIM) {
            const int i = tid;
#pragma unroll
            for (int r = 0; r < 10; ++r) {
                if (row0 + r < nrows) {
                    float hr = ghs[r * G3 + i];
                    float hz = ghs[r * G3 + HDIM + i];
                    float hn = ghs[r * G3 + 2 * HDIM + i];
                    float rg = sigf(xrv[r] + hr);
                    float zg = sigf(xzv[r] + hz);
                    float ng = tanh_fast(xnv[r] + rg * hn);
                    float ho = hT[i * 12 + r];
                    float hnew = (1.f - zg) * ng + zg * ho;
                    hT[i * 12 + r] = hnew;
                    if (t < slen[r]) pacc[r] += hnew;
                }
            }
        }
        __syncthreads();
    }

    if (tid < HDIM) {
#pragma unroll
        for (int r = 0; r < 10; ++r) {
            if (row0 + r < nrows) {
                int L = slen[r];
                pool[(size_t)(row0 + r) * 400 + dirOff + tid] =
                    (L > 0) ? pacc[r] / (float)L : 0.f;
            }
        }
    }
}

// ---------------- heads: doc_pro + sent_pro -> sigmoid -> packed out ------
__global__ __launch_bounds__(256) void head_kernel(
    const float* __restrict__ d_pool, const int* __restrict__ doc_lens,
    const float* __restrict__ doc_w, const float* __restrict__ doc_b,
    const float* __restrict__ sent_w, const float* __restrict__ sent_b,
    float* __restrict__ out)
{
    __shared__ int sdl[ND];
    __shared__ int soff[ND + 1];
    const int tid = threadIdx.x;   // = doc index, one block of 256
    int dl = doc_lens[tid];
    if (dl < 0) dl = 0;
    if (dl > DTR) dl = DTR;
    sdl[tid] = dl;
    __syncthreads();
    if (tid == 0) {
        int run = 0;
        for (int i = 0; i < ND; ++i) { soff[i] = run; run += sdl[i]; }
        soff[ND] = run;
    }
    __syncthreads();

    const float* dv = d_pool + (size_t)tid * 400;
    float dp = doc_b[0];
    for (int f = 0; f < 400; ++f) dp += dv[f] * doc_w[f];
    out[tid] = sigf(dp);

    int base = ND + soff[tid];
    for (int c = 0; c < dl; ++c) {
        float sp = sent_b[c];
        const float* swr = sent_w + c * 400;
        for (int f = 0; f < 400; ++f) sp += dv[f] * swr[f];
        out[base + c] = sigf(sp);
    }
}

// --------------------------------------------------------------------------
extern "C" void kernel_launch(void* const* d_in, const int* in_sizes, int n_in,
                              void* d_out, int out_size, void* d_ws, size_t ws_size,
                              hipStream_t stream) {
    const int*   x        = (const int*)d_in[0];
    // d_in[1] = doc_nums (scalar 256), unused
    const int*   doc_lens = (const int*)d_in[2];
    const float* emb      = (const float*)d_in[3];
    const float* wf_ih = (const float*)d_in[4];
    const float* wf_hh = (const float*)d_in[5];
    const float* wf_bi = (const float*)d_in[6];
    const float* wf_bh = (const float*)d_in[7];
    const float* wb_ih = (const float*)d_in[8];
    const float* wb_hh = (const float*)d_in[9];
    const float* wb_bi = (const float*)d_in[10];
    const float* wb_bh = (const float*)d_in[11];
    const float* sf_ih = (const float*)d_in[12];
    const float* sf_hh = (const float*)d_in[13];
    const float* sf_bi = (const float*)d_in[14];
    const float* sf_bh = (const float*)d_in[15];
    const float* sb_ih = (const float*)d_in[16];
    const float* sb_hh = (const float*)d_in[17];
    const float* sb_bi = (const float*)d_in[18];
    const float* sb_bh = (const float*)d_in[19];
    const float* doc_w  = (const float*)d_in[20];
    const float* doc_b  = (const float*)d_in[21];
    const float* sent_w = (const float*)d_in[22];
    const float* sent_b = (const float*)d_in[23];

    char* ws = (char*)d_ws;
    const size_t OFF_GX  = 0;                                   // 128000*600*2
    const size_t OFF_SIN = 153600000;                           // 2560*400*4
    const size_t OFF_D   = OFF_SIN + 4096000;                   // 256*400*4
    const size_t OFF_SL  = OFF_D + 409600;                      // 2560*4
    const size_t OFF_WT  = OFF_SL + 10240;                      // 4 * 200*600*4
    bf16*  gx    = (bf16*)(ws + OFF_GX);
    float* s_in  = (float*)(ws + OFF_SIN);
    float* dpool = (float*)(ws + OFF_D);
    int*   sl    = (int*)(ws + OFF_SL);
    float* wT0   = (float*)(ws + OFF_WT);
    float* wT1   = wT0 + 120000;
    float* wT2   = wT1 + 120000;
    float* wT3   = wT2 + 120000;

    const int tgrid = (G3 * HDIM + 255) / 256;
    transpose_hh<<<tgrid, 256, 0, stream>>>(wf_hh, wT0);
    transpose_hh<<<tgrid, 256, 0, stream>>>(wb_hh, wT1);
    transpose_hh<<<tgrid, 256, 0, stream>>>(sf_hh, wT2);
    transpose_hh<<<tgrid, 256, 0, stream>>>(sb_hh, wT3);
    lens_kernel<<<(NS + 255) / 256, 256, 0, stream>>>(x, sl);

    // word level, forward dir
    gemm_bias_bf16<<<dim3(128000 / 64, 10), 256, 0, stream>>>(emb, x, wf_ih, wf_bi, gx, 128000, 300);
    gru_kernel<<<NS / 10, 320, 0, stream>>>(gx, wT0, wf_bh, sl, s_in, NS, TW, 0, 0);
    // word level, backward dir
    gemm_bias_bf16<<<dim3(128000 / 64, 10), 256, 0, stream>>>(emb, x, wb_ih, wb_bi, gx, 128000, 300);
    gru_kernel<<<NS / 10, 320, 0, stream>>>(gx, wT1, wb_bh, sl, s_in, NS, TW, 200, 1);
    // sentence level, forward dir (A = s_in, identity gather)
    gemm_bias_bf16<<<dim3(2560 / 64, 10), 256, 0, stream>>>(s_in, nullptr, sf_ih, sf_bi, gx, 2560, 400);
    gru_kernel<<<(ND + 9) / 10, 320, 0, stream>>>(gx, wT2, sf_bh, doc_lens, dpool, ND, DTR, 0, 0);
    // sentence level, backward dir
    gemm_bias_bf16<<<dim3(2560 / 64, 10), 256, 0, stream>>>(s_in, nullptr, sb_ih, sb_bi, gx, 2560, 400);
    gru_kernel<<<(ND + 9) / 10, 320, 0, stream>>>(gx, wT3, sb_bh, doc_lens, dpool, ND, DTR, 200, 1);

    head_kernel<<<1, 256, 0, stream>>>(dpool, doc_lens, doc_w, doc_b, sent_w, sent_b, (float*)d_out);
}

// Round 2
// 2524.098 us; speedup vs baseline: 1.8331x; 1.8331x over previous
//
#include <hip/hip_runtime.h>
#include <hip/hip_bf16.h>

// Hierarchical BiGRU. Round 1: MFMA-ized GRU recurrence.
//  - W_hh (600x200) pre-packed (bf16) into exact 16x16x32 MFMA B-fragment
//    order; each 512-thread block keeps its direction's full W_hh^T in
//    registers (35 frags x 4 VGPR per wave) for all T steps.
//  - h kept as bf16 hi+lo pair in LDS (fp32-accurate recurrence); the K-loop
//    runs twice against the same B registers.
//  - gate combine fp32 in-thread; each thread owns <=7 (row,unit) pairs and
//    keeps h + pool accumulator in registers.
// gx pre-activations still produced by the round-0 vector GEMM (next target).

typedef __hip_bfloat16 bf16;
typedef short s16x8 __attribute__((ext_vector_type(8)));
typedef float f32x4 __attribute__((ext_vector_type(4)));

#define HDIM 200
#define G3   600
#define NS   2560
#define TW   50
#define ND   256
#define DTR  10

// MFMA tiling for the recurrence: M=16 rows, N padded 600->640 (40 tiles),
// K padded 200->224 (7 chunks of 32).
#define NTILES 40
#define KCH    7
#define HSTR   232   // padded K stride for h in LDS (bf16 elems)
#define GSTR   650   // padded N stride for gh in LDS (f32 elems)

__device__ __forceinline__ float sigf(float x) { return 1.f / (1.f + __expf(-x)); }
__device__ __forceinline__ float tanh_fast(float x) {
    float e = __expf(2.f * x);
    return (e - 1.f) / (e + 1.f);
}
__device__ __forceinline__ unsigned short f2bf(float f) {
    unsigned u = __float_as_uint(f);
    unsigned r = (u + 0x7FFFu + ((u >> 16) & 1u)) >> 16;
    return (unsigned short)r;
}
__device__ __forceinline__ float bf2f(unsigned short b) {
    return __uint_as_float(((unsigned)b) << 16);
}

// ---------------- sentence lengths: count of nonzero tokens ----------------
__global__ void lens_kernel(const int* __restrict__ x, int* __restrict__ sl) {
    int s = blockIdx.x * 256 + threadIdx.x;
    if (s < NS) {
        int c = 0;
        for (int t = 0; t < TW; ++t) c += (x[s * TW + t] != 0) ? 1 : 0;
        sl[s] = c;
    }
}

// ------------- pre-pack W_hh (600x200 f32) into MFMA B-fragments ----------
// Bp[((d*40+tile)*7+kc)*64 + lane] = 8 bf16: B[k=kc*32+(lane>>4)*8+j][n=tile*16+(lane&15)]
// where B[k][n] = W_hh[n][k].
__global__ void prepack_whh(const float* __restrict__ w0, const float* __restrict__ w1,
                            const float* __restrict__ w2, const float* __restrict__ w3,
                            bf16* __restrict__ Bp) {
    int gid = blockIdx.x * 256 + threadIdx.x;
    if (gid >= 4 * NTILES * KCH * 64) return;
    int lane = gid & 63;
    int f = gid >> 6;
    int kc = f % KCH;
    int tile = (f / KCH) % NTILES;
    int d = f / (KCH * NTILES);
    const float* w = (d == 0) ? w0 : (d == 1) ? w1 : (d == 2) ? w2 : w3;
    int n = tile * 16 + (lane & 15);
    int kb = kc * 32 + (lane >> 4) * 8;
    unsigned short vals[8] __attribute__((aligned(16)));
#pragma unroll
    for (int j = 0; j < 8; ++j) {
        int k = kb + j;
        float v = (n < G3 && k < HDIM) ? w[n * HDIM + k] : 0.f;
        vals[j] = f2bf(v);
    }
    *reinterpret_cast<float4*>(reinterpret_cast<char*>(Bp) + (size_t)gid * 16) =
        *reinterpret_cast<const float4*>(vals);
}

// ---------------- GEMM: C[M][600] = gatherA[M][K] * W[600][K]^T + bias -----
__global__ __launch_bounds__(256) void gemm_bias_bf16(
    const float* __restrict__ A, const int* __restrict__ idx,
    const float* __restrict__ W, const float* __restrict__ bias,
    bf16* __restrict__ C, int M, int K)
{
    __shared__ float As[16][68];
    __shared__ float Bs[16][68];
    __shared__ int toks[64];

    const int tid = threadIdx.x;
    const int r0 = blockIdx.x * 64;
    const int g0 = blockIdx.y * 64;
    if (tid < 64) {
        int r = r0 + tid;
        toks[tid] = idx ? idx[r] : r;
    }
    const int kk = tid & 15;
    const int rq = tid >> 4;
    const int tx = tid & 15;
    const int ty = tid >> 4;
    float c[4][4] = {};
    __syncthreads();

    for (int k0 = 0; k0 < K; k0 += 16) {
        const bool kv = (k0 + kk) < K;
#pragma unroll
        for (int p = 0; p < 4; ++p) {
            int r = rq * 4 + p;
            float av = 0.f;
            if (kv) av = A[(size_t)toks[r] * K + k0 + kk];
            As[kk][r] = av;
            int gg = g0 + r;
            float wv = 0.f;
            if (kv && gg < G3) wv = W[(size_t)gg * K + k0 + kk];
            Bs[kk][r] = wv;
        }
        __syncthreads();
#pragma unroll
        for (int kq = 0; kq < 16; ++kq) {
            float4 a = *(const float4*)&As[kq][ty * 4];
            float4 b = *(const float4*)&Bs[kq][tx * 4];
            float av[4] = {a.x, a.y, a.z, a.w};
            float bv[4] = {b.x, b.y, b.z, b.w};
#pragma unroll
            for (int i = 0; i < 4; ++i)
#pragma unroll
                for (int j = 0; j < 4; ++j)
                    c[i][j] += av[i] * bv[j];
        }
        __syncthreads();
    }

#pragma unroll
    for (int i = 0; i < 4; ++i) {
        int r = r0 + ty * 4 + i;
#pragma unroll
        for (int j = 0; j < 4; ++j) {
            int gg = g0 + tx * 4 + j;
            if (gg < G3) {
                float v = c[i][j] + bias[gg];
                C[(size_t)r * G3 + gg] = __float2bfloat16(v);
            }
        }
    }
}

// ---------------- MFMA GRU recurrence + online masked avg-pool -------------
// One block = 16 batch rows, all T steps, one direction. 512 threads, 8 waves.
// Wave w owns N-tiles [w*5, w*5+5) with B fragments resident in registers.
__global__ __launch_bounds__(512, 2) void gru_mfma(
    const bf16* __restrict__ gx, const bf16* __restrict__ Bp, int dirBase,
    const float* __restrict__ bh, const int* __restrict__ lens,
    float* __restrict__ pool, int T, int dirOff, int rev)
{
    __shared__ float ghs[16 * GSTR];                         // 41.6 KB
    __shared__ __align__(16) unsigned short hhi[16 * HSTR];  // 7.4 KB
    __shared__ __align__(16) unsigned short hlo[16 * HSTR];  // 7.4 KB
    __shared__ float bhs[G3];
    __shared__ int slen[16];

    const int tid = threadIdx.x;
    const int wv = tid >> 6;
    const int lane = tid & 63;
    const int row0 = blockIdx.x * 16;

    for (int i = tid; i < 16 * HSTR; i += 512) { hhi[i] = 0; hlo[i] = 0; }
    for (int i = tid; i < G3; i += 512) bhs[i] = bh[i];
    if (tid < 16) {
        int L = lens[row0 + tid];
        if (L < 0) L = 0;
        if (L > T) L = T;
        slen[tid] = L;
    }

    // resident B fragments: 5 tiles x 7 K-chunks per wave
    s16x8 bfrag[5][7];
    {
        const float4* Bq = reinterpret_cast<const float4*>(Bp);
#pragma unroll
        for (int t5 = 0; t5 < 5; ++t5)
#pragma unroll
            for (int kc = 0; kc < KCH; ++kc) {
                int f = (dirBase + wv * 5 + t5) * KCH + kc;
                float4 raw = Bq[(size_t)f * 64 + lane];
                bfrag[t5][kc] = *reinterpret_cast<s16x8*>(&raw);
            }
    }

    // per-thread gate-unit ownership: u = tid + q*512, u = r*200 + i
    bool vld[7];
    int ur[7], ui[7];
    size_t goff[7];
    float hreg[7], pacc[7];
#pragma unroll
    for (int q = 0; q < 7; ++q) {
        int u = tid + q * 512;
        vld[q] = (u < 16 * HDIM);
        int r = vld[q] ? (u / HDIM) : 0;
        int i = vld[q] ? (u % HDIM) : 0;
        ur[q] = r; ui[q] = i;
        goff[q] = ((size_t)(row0 + r) * T) * G3 + i;
        hreg[q] = 0.f; pacc[q] = 0.f;
    }

    const int am = (lane & 15) * HSTR + (lane >> 4) * 8;  // A-frag base (elems)
    __syncthreads();

    for (int ts = 0; ts < T; ++ts) {
        const int t = rev ? (T - 1 - ts) : ts;

        // issue gx loads for this step (consumed in combine, after the MFMAs)
        unsigned short xr[7], xz[7], xn[7];
#pragma unroll
        for (int q = 0; q < 7; ++q) {
            if (vld[q]) {
                const unsigned short* gp =
                    reinterpret_cast<const unsigned short*>(gx) + goff[q] + (size_t)t * G3;
                xr[q] = gp[0];
                xz[q] = gp[HDIM];
                xn[q] = gp[2 * HDIM];
            }
        }

        // gh = h @ W_hh^T via MFMA (hi + lo passes share B registers)
        f32x4 acc[5];
#pragma unroll
        for (int t5 = 0; t5 < 5; ++t5) acc[t5] = (f32x4){0.f, 0.f, 0.f, 0.f};
#pragma unroll
        for (int kc = 0; kc < KCH; ++kc) {
            s16x8 a = *reinterpret_cast<const s16x8*>(&hhi[am + kc * 32]);
#pragma unroll
            for (int t5 = 0; t5 < 5; ++t5)
                acc[t5] = __builtin_amdgcn_mfma_f32_16x16x32_bf16(a, bfrag[t5][kc], acc[t5], 0, 0, 0);
        }
#pragma unroll
        for (int kc = 0; kc < KCH; ++kc) {
            s16x8 a = *reinterpret_cast<const s16x8*>(&hlo[am + kc * 32]);
#pragma unroll
            for (int t5 = 0; t5 < 5; ++t5)
                acc[t5] = __builtin_amdgcn_mfma_f32_16x16x32_bf16(a, bfrag[t5][kc], acc[t5], 0, 0, 0);
        }

        // C layout: col = lane&15, row = (lane>>4)*4 + reg
#pragma unroll
        for (int t5 = 0; t5 < 5; ++t5) {
            int col = (wv * 5 + t5) * 16 + (lane & 15);
#pragma unroll
            for (int rg = 0; rg < 4; ++rg)
                ghs[((lane >> 4) * 4 + rg) * GSTR + col] = acc[t5][rg];
        }
        __syncthreads();

        // gate combine (fp32, in-thread h)
#pragma unroll
        for (int q = 0; q < 7; ++q) {
            if (vld[q]) {
                int r = ur[q], i = ui[q];
                float ghr = ghs[r * GSTR + i] + bhs[i];
                float ghz = ghs[r * GSTR + HDIM + i] + bhs[HDIM + i];
                float ghn = ghs[r * GSTR + 2 * HDIM + i] + bhs[2 * HDIM + i];
                float rg = sigf(bf2f(xr[q]) + ghr);
                float zg = sigf(bf2f(xz[q]) + ghz);
                float ng = tanh_fast(bf2f(xn[q]) + rg * ghn);
                float hnew = (1.f - zg) * ng + zg * hreg[q];
                hreg[q] = hnew;
                unsigned short hi = f2bf(hnew);
                hhi[r * HSTR + i] = hi;
                hlo[r * HSTR + i] = f2bf(hnew - bf2f(hi));
                if (t < slen[r]) pacc[q] += hnew;
            }
        }
        __syncthreads();
    }

#pragma unroll
    for (int q = 0; q < 7; ++q) {
        if (vld[q]) {
            int L = slen[ur[q]];
            pool[(size_t)(row0 + ur[q]) * 400 + dirOff + ui[q]] =
                (L > 0) ? pacc[q] / (float)L : 0.f;
        }
    }
}

// ---------------- heads: doc_pro + sent_pro -> sigmoid -> packed out ------
__global__ __launch_bounds__(256) void head_kernel(
    const float* __restrict__ d_pool, const int* __restrict__ doc_lens,
    const float* __restrict__ doc_w, const float* __restrict__ doc_b,
    const float* __restrict__ sent_w, const float* __restrict__ sent_b,
    float* __restrict__ out)
{
    __shared__ int sdl[ND];
    __shared__ int soff[ND + 1];
    const int tid = threadIdx.x;
    int dl = doc_lens[tid];
    if (dl < 0) dl = 0;
    if (dl > DTR) dl = DTR;
    sdl[tid] = dl;
    __syncthreads();
    if (tid == 0) {
        int run = 0;
        for (int i = 0; i < ND; ++i) { soff[i] = run; run += sdl[i]; }
        soff[ND] = run;
    }
    __syncthreads();

    const float* dv = d_pool + (size_t)tid * 400;
    float dp = doc_b[0];
    for (int f = 0; f < 400; ++f) dp += dv[f] * doc_w[f];
    out[tid] = sigf(dp);

    int base = ND + soff[tid];
    for (int c = 0; c < dl; ++c) {
        float sp = sent_b[c];
        const float* swr = sent_w + c * 400;
        for (int f = 0; f < 400; ++f) sp += dv[f] * swr[f];
        out[base + c] = sigf(sp);
    }
}

// --------------------------------------------------------------------------
extern "C" void kernel_launch(void* const* d_in, const int* in_sizes, int n_in,
                              void* d_out, int out_size, void* d_ws, size_t ws_size,
                              hipStream_t stream) {
    const int*   x        = (const int*)d_in[0];
    const int*   doc_lens = (const int*)d_in[2];
    const float* emb      = (const float*)d_in[3];
    const float* wf_ih = (const float*)d_in[4];
    const float* wf_hh = (const float*)d_in[5];
    const float* wf_bi = (const float*)d_in[6];
    const float* wf_bh = (const float*)d_in[7];
    const float* wb_ih = (const float*)d_in[8];
    const float* wb_hh = (const float*)d_in[9];
    const float* wb_bi = (const float*)d_in[10];
    const float* wb_bh = (const float*)d_in[11];
    const float* sf_ih = (const float*)d_in[12];
    const float* sf_hh = (const float*)d_in[13];
    const float* sf_bi = (const float*)d_in[14];
    const float* sf_bh = (const float*)d_in[15];
    const float* sb_ih = (const float*)d_in[16];
    const float* sb_hh = (const float*)d_in[17];
    const float* sb_bi = (const float*)d_in[18];
    const float* sb_bh = (const float*)d_in[19];
    const float* doc_w  = (const float*)d_in[20];
    const float* doc_b  = (const float*)d_in[21];
    const float* sent_w = (const float*)d_in[22];
    const float* sent_b = (const float*)d_in[23];

    char* ws = (char*)d_ws;
    const size_t OFF_GX  = 0;                       // 128000*600*2   = 153.6 MB
    const size_t OFF_SIN = 153600000;               // 2560*400*4    = 4.096 MB
    const size_t OFF_D   = OFF_SIN + 4096000;       // 256*400*4
    const size_t OFF_SL  = OFF_D + 409600;          // 2560*4
    const size_t OFF_BP  = OFF_SL + 10240;          // 4*40*7*64*8 bf16 = 1.147 MB
    bf16*  gx    = (bf16*)(ws + OFF_GX);
    float* s_in  = (float*)(ws + OFF_SIN);
    float* dpool = (float*)(ws + OFF_D);
    int*   sl    = (int*)(ws + OFF_SL);
    bf16*  Bpack = (bf16*)(ws + OFF_BP);

    prepack_whh<<<(4 * NTILES * KCH * 64 + 255) / 256, 256, 0, stream>>>(
        wf_hh, wb_hh, sf_hh, sb_hh, Bpack);
    lens_kernel<<<(NS + 255) / 256, 256, 0, stream>>>(x, sl);

    // word level, forward dir
    gemm_bias_bf16<<<dim3(128000 / 64, 10), 256, 0, stream>>>(emb, x, wf_ih, wf_bi, gx, 128000, 300);
    gru_mfma<<<NS / 16, 512, 0, stream>>>(gx, Bpack, 0, wf_bh, sl, s_in, TW, 0, 0);
    // word level, backward dir
    gemm_bias_bf16<<<dim3(128000 / 64, 10), 256, 0, stream>>>(emb, x, wb_ih, wb_bi, gx, 128000, 300);
    gru_mfma<<<NS / 16, 512, 0, stream>>>(gx, Bpack, NTILES, wb_bh, sl, s_in, TW, 200, 1);
    // sentence level, forward dir (A = s_in, identity gather)
    gemm_bias_bf16<<<dim3(2560 / 64, 10), 256, 0, stream>>>(s_in, nullptr, sf_ih, sf_bi, gx, 2560, 400);
    gru_mfma<<<ND / 16, 512, 0, stream>>>(gx, Bpack, 2 * NTILES, sf_bh, doc_lens, dpool, DTR, 0, 0);
    // sentence level, backward dir
    gemm_bias_bf16<<<dim3(2560 / 64, 10), 256, 0, stream>>>(s_in, nullptr, sb_ih, sb_bi, gx, 2560, 400);
    gru_mfma<<<ND / 16, 512, 0, stream>>>(gx, Bpack, 3 * NTILES, sb_bh, doc_lens, dpool, DTR, 200, 1);

    head_kernel<<<1, 256, 0, stream>>>(dpool, doc_lens, doc_w, doc_b, sent_w, sent_b, (float*)d_out);
}

// Round 5
// 1974.025 us; speedup vs baseline: 2.3439x; 1.2787x over previous
//
#include <hip/hip_runtime.h>
#include <hip/hip_bf16.h>

// Hierarchical BiGRU. Round 5: fix n-gate bias fusion bug from rounds 3/4.
//   GRU math: r=sig(xr+bi_r + hr+bh_r), z likewise (biases fusable), but
//   n = tanh(xn + bi_n + r*(hn + bh_n)) -- bi_n must stay OUTSIDE r*(...).
//   Rounds 3/4 fused bi_n into the r-multiplied term: deterministic ~0.02
//   error, independent of precision changes (hence identical absmax).
//  - gemm_mfma: 128x128 tile, 16x16x32 bf16, 3-pass compensated
//    (Ahi*Bhi + Ahi*Blo + Alo*Bhi) => gx numerically == fp32 GEMM + bf16
//    store (round-1-proven numerics). Fragment-layout coalesced stores.
//  - gru_mfma: W_hh resident in registers, h hi/lo compensated, fp32
//    combine; reads gx in fragment layout; bhs split per-gate (fix above).
// ws ~167 MB.

typedef __hip_bfloat16 bf16;
typedef short s16x8 __attribute__((ext_vector_type(8)));
typedef float f32x4 __attribute__((ext_vector_type(4)));

#define HDIM 200
#define G3   600
#define NS   2560
#define TW   50
#define ND   256
#define DTR  10

#define NT_STORE 38      // stored n-tiles (608 cols >= 600)
#define NTILES   40      // packed-B n-tiles (640 cols, zero pad)
#define KCH      7       // W_hh k-chunks (200 -> 224)
#define HSTR     232
#define GSTR     650
#define KC_W     10      // word x-proj k-chunks (300 -> 320)
#define KC_S     13      // sent x-proj k-chunks (400 -> 416)
#define SSTR     416     // s_in row stride (f32 elems)
#define EMB_ELEMS 15000000
#define MTB      19456   // NT_STORE*512 bytes per 16-row group

__device__ __forceinline__ float sigf(float x) { return 1.f / (1.f + __expf(-x)); }
__device__ __forceinline__ float tanh_fast(float x) {
    float e = __expf(2.f * x);
    return (e - 1.f) / (e + 1.f);
}
__device__ __forceinline__ unsigned short f2bf(float f) {
    unsigned u = __float_as_uint(f);
    unsigned r = (u + 0x7FFFu + ((u >> 16) & 1u)) >> 16;
    return (unsigned short)r;
}
__device__ __forceinline__ float bf2f(unsigned short b) {
    return __uint_as_float(((unsigned)b) << 16);
}
// pack 2 f32 -> 2 bf16 (round-half-away), a in low short, b in high
__device__ __forceinline__ unsigned pk_bf(float a, float b) {
    unsigned ua = __float_as_uint(a) + 0x8000u;
    unsigned ub = __float_as_uint(b) + 0x8000u;
    return __builtin_amdgcn_perm(ub, ua, 0x07060302);
}
// split pair into hi pack + lo pack (hi rounding identical to pk_bf)
__device__ __forceinline__ void split2(float a, float b, unsigned& hi, unsigned& lo) {
    unsigned ua = __float_as_uint(a) + 0x8000u;
    unsigned ub = __float_as_uint(b) + 0x8000u;
    hi = __builtin_amdgcn_perm(ub, ua, 0x07060302);
    float ha = __uint_as_float(ua & 0xFFFF0000u);
    float hb = __uint_as_float(ub & 0xFFFF0000u);
    lo = pk_bf(a - ha, b - hb);
}

// ---------------- sentence lengths ----------------
__global__ void lens_kernel(const int* __restrict__ x, int* __restrict__ sl) {
    int s = blockIdx.x * 256 + threadIdx.x;
    if (s < NS) {
        int c = 0;
        for (int t = 0; t < TW; ++t) c += (x[s * TW + t] != 0) ? 1 : 0;
        sl[s] = c;
    }
}

__global__ void zero_u32(unsigned* __restrict__ p, int n) {
    int i = blockIdx.x * 256 + threadIdx.x;
    if (i < n) p[i] = 0u;
}

// ------------- pre-pack W_hh (600x200 f32) into MFMA B-fragments (hi only)
__global__ void prepack_whh(const float* __restrict__ w0, const float* __restrict__ w1,
                            const float* __restrict__ w2, const float* __restrict__ w3,
                            bf16* __restrict__ Bp) {
    int gid = blockIdx.x * 256 + threadIdx.x;
    if (gid >= 4 * NTILES * KCH * 64) return;
    int lane = gid & 63;
    int f = gid >> 6;
    int kc = f % KCH;
    int tile = (f / KCH) % NTILES;
    int d = f / (KCH * NTILES);
    const float* w = (d == 0) ? w0 : (d == 1) ? w1 : (d == 2) ? w2 : w3;
    int n = tile * 16 + (lane & 15);
    int kb = kc * 32 + (lane >> 4) * 8;
    unsigned short vals[8] __attribute__((aligned(16)));
#pragma unroll
    for (int j = 0; j < 8; ++j) {
        int k = kb + j;
        float v = (n < G3 && k < HDIM) ? w[n * HDIM + k] : 0.f;
        vals[j] = f2bf(v);
    }
    *reinterpret_cast<float4*>(reinterpret_cast<char*>(Bp) + (size_t)gid * 16) =
        *reinterpret_cast<const float4*>(vals);
}

// ------------- pre-pack W_ih (600 x Kin f32) into hi+lo MFMA B-fragments --
// layout: uint4 index ((nt*KC + kc)*2 + part)*64 + lane
__global__ void prepack_bih(const float* __restrict__ w, bf16* __restrict__ Bp,
                            int Kin, int KC) {
    int gid = blockIdx.x * 256 + threadIdx.x;
    if (gid >= NTILES * KC * 64) return;
    int lane = gid & 63;
    int f = gid >> 6;
    int kc = f % KC;
    int nt = f / KC;
    int n = nt * 16 + (lane & 15);
    int kb = kc * 32 + (lane >> 4) * 8;
    unsigned hi[4], lo[4];
#pragma unroll
    for (int p = 0; p < 4; ++p) {
        int k0 = kb + p * 2, k1 = kb + p * 2 + 1;
        float v0 = (n < G3 && k0 < Kin) ? w[n * Kin + k0] : 0.f;
        float v1 = (n < G3 && k1 < Kin) ? w[n * Kin + k1] : 0.f;
        split2(v0, v1, hi[p], lo[p]);
    }
    uint4* bq = reinterpret_cast<uint4*>(Bp);
    bq[(size_t)(f * 2 + 0) * 64 + lane] = make_uint4(hi[0], hi[1], hi[2], hi[3]);
    bq[(size_t)(f * 2 + 1) * 64 + lane] = make_uint4(lo[0], lo[1], lo[2], lo[3]);
}

// ---------------- MFMA GEMM (compensated): gx_frag = A @ B ----------------
// grid (M/128, 5). GATHER: A row = emb[x[row]] f32. else: A = Afl f32
// (astride f32/row). Output single-bf16 fragment layout:
// byte = ((gmt*38 + gnt)*64 + lane)*8 + reg*2.
template<bool GATHER>
__global__ __launch_bounds__(256) void gemm_mfma(
    const float* __restrict__ Aemb, const float* __restrict__ Afl, int astride,
    const int* __restrict__ idx, const bf16* __restrict__ Bp, int KC,
    bf16* __restrict__ gxOut)
{
    __shared__ __align__(16) unsigned short Ahi[128 * 32];  // 8 KB, swizzled
    __shared__ __align__(16) unsigned short Alo[128 * 32];  // 8 KB
    __shared__ int toks[128];

    const int tid = threadIdx.x;
    const int wv = tid >> 6, lane = tid & 63;
    const int bm = blockIdx.x, bn = blockIdx.y;

    if (GATHER && tid < 128) toks[tid] = idx[bm * 128 + tid];

    // A-fragment read addresses (ushort units), constant across kc
    int aaddr[4];
#pragma unroll
    for (int mt = 0; mt < 4; ++mt) {
        int row = (wv & 1) * 64 + mt * 16 + (lane & 15);
        aaddr[mt] = row * 32 + (((lane >> 4) ^ ((row >> 1) & 3)) << 3);
    }

    // staging: thread -> (row srow, k-half kh); 16 f32 per thread per kc
    const int srow = tid >> 1, kh = tid & 1;
    const int ssw = (srow >> 1) & 3;

    f32x4 acc[4][4];
#pragma unroll
    for (int i = 0; i < 4; ++i)
#pragma unroll
        for (int j = 0; j < 4; ++j) acc[i][j] = (f32x4){0.f, 0.f, 0.f, 0.f};

    const uint4* bq = reinterpret_cast<const uint4*>(Bp);
    int gnt[4];
#pragma unroll
    for (int j = 0; j < 4; ++j) gnt[j] = bn * 8 + (wv >> 1) * 4 + j;

    __syncthreads();  // toks visible
    const int obase = GATHER ? (toks[srow] * 300 + kh * 16) : 0;
    const float* arow = GATHER ? nullptr
        : Afl + (size_t)(bm * 128 + srow) * astride + kh * 16;

    for (int kc = 0; kc < KC; ++kc) {
        // B hi+lo fragments straight from L2
        uint4 bhi[4], blo[4];
#pragma unroll
        for (int j = 0; j < 4; ++j) {
            size_t fb = (size_t)(gnt[j] * KC + kc) * 2 * 64;
            bhi[j] = bq[fb + lane];
            blo[j] = bq[fb + 64 + lane];
        }

        __syncthreads();  // prior iter's ds_reads done

        // load 16 f32 of A for this (row, k-half)
        float4 f[4];
        if (GATHER) {
            int ob = obase + kc * 32;
#pragma unroll
            for (int j = 0; j < 4; ++j) {
                int o = ob + j * 4;
                o = (o > EMB_ELEMS - 4) ? (EMB_ELEMS - 4) : o;  // clamp (dead k)
                f[j] = *reinterpret_cast<const float4*>(Aemb + o);
            }
        } else {
#pragma unroll
            for (int j = 0; j < 4; ++j)
                f[j] = *reinterpret_cast<const float4*>(arow + kc * 32 + j * 4);
        }
        // split hi/lo and store swizzled
#pragma unroll
        for (int g = 0; g < 2; ++g) {
            uint4 vh, vl;
            split2(f[g * 2].x, f[g * 2].y, vh.x, vl.x);
            split2(f[g * 2].z, f[g * 2].w, vh.y, vl.y);
            split2(f[g * 2 + 1].x, f[g * 2 + 1].y, vh.z, vl.z);
            split2(f[g * 2 + 1].z, f[g * 2 + 1].w, vh.w, vl.w);
            int slot = (kh * 2 + g) ^ ssw;
            *reinterpret_cast<uint4*>(&Ahi[srow * 32 + slot * 8]) = vh;
            *reinterpret_cast<uint4*>(&Alo[srow * 32 + slot * 8]) = vl;
        }
        __syncthreads();

        s16x8 ah[4], al[4];
#pragma unroll
        for (int mt = 0; mt < 4; ++mt) {
            ah[mt] = *reinterpret_cast<const s16x8*>(&Ahi[aaddr[mt]]);
            al[mt] = *reinterpret_cast<const s16x8*>(&Alo[aaddr[mt]]);
        }
#pragma unroll
        for (int mt = 0; mt < 4; ++mt)
#pragma unroll
            for (int j = 0; j < 4; ++j) {
                acc[mt][j] = __builtin_amdgcn_mfma_f32_16x16x32_bf16(
                    ah[mt], *reinterpret_cast<const s16x8*>(&bhi[j]), acc[mt][j], 0, 0, 0);
                acc[mt][j] = __builtin_amdgcn_mfma_f32_16x16x32_bf16(
                    ah[mt], *reinterpret_cast<const s16x8*>(&blo[j]), acc[mt][j], 0, 0, 0);
                acc[mt][j] = __builtin_amdgcn_mfma_f32_16x16x32_bf16(
                    al[mt], *reinterpret_cast<const s16x8*>(&bhi[j]), acc[mt][j], 0, 0, 0);
            }
    }

    // epilogue: fragment-layout coalesced stores
#pragma unroll
    for (int mt = 0; mt < 4; ++mt) {
        int gmt = bm * 8 + (wv & 1) * 4 + mt;
#pragma unroll
        for (int j = 0; j < 4; ++j) {
            if (gnt[j] < NT_STORE) {
                uint2 v;
                v.x = pk_bf(acc[mt][j][0], acc[mt][j][1]);
                v.y = pk_bf(acc[mt][j][2], acc[mt][j][3]);
                *reinterpret_cast<uint2*>(reinterpret_cast<char*>(gxOut) +
                    ((size_t)(gmt * NT_STORE + gnt[j]) * 64 + lane) * 8) = v;
            }
        }
    }
}

// ---------------- MFMA GRU recurrence + online masked avg-pool -------------
// bhs[0..2H) = bh+bi (r,z gates: fusion valid); bhs[2H..3H) = bh only;
// bin[i] = bi[2H+i] added OUTSIDE the r-multiplied term (n-gate fix).
__global__ __launch_bounds__(512, 2) void gru_mfma(
    const bf16* __restrict__ gx, const bf16* __restrict__ Bp, int dirBase,
    const float* __restrict__ bh, const float* __restrict__ bi,
    const int* __restrict__ lens,
    float* __restrict__ pool, int poolStride,
    int T, int dirOff, int rev)
{
    __shared__ float ghs[16 * GSTR];
    __shared__ __align__(16) unsigned short hhi[16 * HSTR];
    __shared__ __align__(16) unsigned short hlo[16 * HSTR];
    __shared__ float bhs[G3];
    __shared__ float bin[HDIM];
    __shared__ int slen[16];

    const int tid = threadIdx.x;
    const int wv = tid >> 6;
    const int lane = tid & 63;
    const int row0 = blockIdx.x * 16;

    for (int i = tid; i < 16 * HSTR; i += 512) { hhi[i] = 0; hlo[i] = 0; }
    for (int i = tid; i < G3; i += 512)
        bhs[i] = (i < 2 * HDIM) ? (bh[i] + bi[i]) : bh[i];
    if (tid < HDIM) bin[tid] = bi[2 * HDIM + tid];
    if (tid < 16) {
        int L = lens[row0 + tid];
        if (L < 0) L = 0;
        if (L > T) L = T;
        slen[tid] = L;
    }

    s16x8 bfrag[5][7];
    {
        const float4* Bq = reinterpret_cast<const float4*>(Bp);
#pragma unroll
        for (int t5 = 0; t5 < 5; ++t5)
#pragma unroll
            for (int kc = 0; kc < KCH; ++kc) {
                int f = (dirBase + wv * 5 + t5) * KCH + kc;
                float4 raw = Bq[(size_t)f * 64 + lane];
                bfrag[t5][kc] = *reinterpret_cast<s16x8*>(&raw);
            }
    }

    // per-thread gate-unit ownership: u = tid + q*512 = r*200 + i
    bool vld[7];
    int ur[7], ui[7], grb[7], ca0[7], ca1[7], ca2[7];
    float hreg[7], pacc[7];
#pragma unroll
    for (int q = 0; q < 7; ++q) {
        int u = tid + q * 512;
        vld[q] = (u < 16 * HDIM);
        int r = vld[q] ? (u / HDIM) : 0;
        int i = vld[q] ? (u % HDIM) : 0;
        ur[q] = r; ui[q] = i;
        grb[q] = (row0 + r) * T;
        int c0 = i, c1 = i + HDIM, c2 = i + 2 * HDIM;
        ca0[q] = (c0 >> 4) * 512 + (c0 & 15) * 8;
        ca1[q] = (c1 >> 4) * 512 + (c1 & 15) * 8;
        ca2[q] = (c2 >> 4) * 512 + (c2 & 15) * 8;
        hreg[q] = 0.f; pacc[q] = 0.f;
    }

    const char* gxb = reinterpret_cast<const char*>(gx);
    const int am = (lane & 15) * HSTR + (lane >> 4) * 8;
    __syncthreads();

    for (int ts = 0; ts < T; ++ts) {
        const int t = rev ? (T - 1 - ts) : ts;

        unsigned short xr[7], xz[7], xn[7];
#pragma unroll
        for (int q = 0; q < 7; ++q) {
            if (vld[q]) {
                int gr = grb[q] + t;
                int rb = (gr >> 4) * MTB + ((gr >> 2) & 3) * 128 + (gr & 3) * 2;
                xr[q] = *reinterpret_cast<const unsigned short*>(gxb + rb + ca0[q]);
                xz[q] = *reinterpret_cast<const unsigned short*>(gxb + rb + ca1[q]);
                xn[q] = *reinterpret_cast<const unsigned short*>(gxb + rb + ca2[q]);
            }
        }

        f32x4 acc[5];
#pragma unroll
        for (int t5 = 0; t5 < 5; ++t5) acc[t5] = (f32x4){0.f, 0.f, 0.f, 0.f};
#pragma unroll
        for (int kc = 0; kc < KCH; ++kc) {
            s16x8 a = *reinterpret_cast<const s16x8*>(&hhi[am + kc * 32]);
#pragma unroll
            for (int t5 = 0; t5 < 5; ++t5)
                acc[t5] = __builtin_amdgcn_mfma_f32_16x16x32_bf16(a, bfrag[t5][kc], acc[t5], 0, 0, 0);
        }
#pragma unroll
        for (int kc = 0; kc < KCH; ++kc) {
            s16x8 a = *reinterpret_cast<const s16x8*>(&hlo[am + kc * 32]);
#pragma unroll
            for (int t5 = 0; t5 < 5; ++t5)
                acc[t5] = __builtin_amdgcn_mfma_f32_16x16x32_bf16(a, bfrag[t5][kc], acc[t5], 0, 0, 0);
        }

#pragma unroll
        for (int t5 = 0; t5 < 5; ++t5) {
            int col = (wv * 5 + t5) * 16 + (lane & 15);
#pragma unroll
            for (int rg = 0; rg < 4; ++rg)
                ghs[((lane >> 4) * 4 + rg) * GSTR + col] = acc[t5][rg];
        }
        __syncthreads();

#pragma unroll
        for (int q = 0; q < 7; ++q) {
            if (vld[q]) {
                int r = ur[q], i = ui[q];
                float ghr = ghs[r * GSTR + i] + bhs[i];
                float ghz = ghs[r * GSTR + HDIM + i] + bhs[HDIM + i];
                float ghn = ghs[r * GSTR + 2 * HDIM + i] + bhs[2 * HDIM + i];
                float rg = sigf(bf2f(xr[q]) + ghr);
                float zg = sigf(bf2f(xz[q]) + ghz);
                float ng = tanh_fast((bf2f(xn[q]) + bin[i]) + rg * ghn);
                float hnew = (1.f - zg) * ng + zg * hreg[q];
                hreg[q] = hnew;
                unsigned short hi = f2bf(hnew);
                hhi[r * HSTR + i] = hi;
                hlo[r * HSTR + i] = f2bf(hnew - bf2f(hi));
                if (t < slen[r]) pacc[q] += hnew;
            }
        }
        __syncthreads();
    }

#pragma unroll
    for (int q = 0; q < 7; ++q) {
        if (vld[q]) {
            int L = slen[ur[q]];
            pool[(size_t)(row0 + ur[q]) * poolStride + dirOff + ui[q]] =
                (L > 0) ? pacc[q] / (float)L : 0.f;
        }
    }
}

// ---------------- heads ----------------
__global__ __launch_bounds__(256) void head_kernel(
    const float* __restrict__ d_pool, const int* __restrict__ doc_lens,
    const float* __restrict__ doc_w, const float* __restrict__ doc_b,
    const float* __restrict__ sent_w, const float* __restrict__ sent_b,
    float* __restrict__ out)
{
    __shared__ int sdl[ND];
    __shared__ int soff[ND + 1];
    const int tid = threadIdx.x;
    int dl = doc_lens[tid];
    if (dl < 0) dl = 0;
    if (dl > DTR) dl = DTR;
    sdl[tid] = dl;
    __syncthreads();
    if (tid == 0) {
        int run = 0;
        for (int i = 0; i < ND; ++i) { soff[i] = run; run += sdl[i]; }
        soff[ND] = run;
    }
    __syncthreads();

    const float* dv = d_pool + (size_t)tid * 400;
    float dp = doc_b[0];
    for (int f = 0; f < 400; ++f) dp += dv[f] * doc_w[f];
    out[tid] = sigf(dp);

    int base = ND + soff[tid];
    for (int c = 0; c < dl; ++c) {
        float sp = sent_b[c];
        const float* swr = sent_w + c * 400;
        for (int f = 0; f < 400; ++f) sp += dv[f] * swr[f];
        out[base + c] = sigf(sp);
    }
}

// --------------------------------------------------------------------------
extern "C" void kernel_launch(void* const* d_in, const int* in_sizes, int n_in,
                              void* d_out, int out_size, void* d_ws, size_t ws_size,
                              hipStream_t stream) {
    const int*   x        = (const int*)d_in[0];
    const int*   doc_lens = (const int*)d_in[2];
    const float* emb      = (const float*)d_in[3];
    const float* wf_ih = (const float*)d_in[4];
    const float* wf_hh = (const float*)d_in[5];
    const float* wf_bi = (const float*)d_in[6];
    const float* wf_bh = (const float*)d_in[7];
    const float* wb_ih = (const float*)d_in[8];
    const float* wb_hh = (const float*)d_in[9];
    const float* wb_bi = (const float*)d_in[10];
    const float* wb_bh = (const float*)d_in[11];
    const float* sf_ih = (const float*)d_in[12];
    const float* sf_hh = (const float*)d_in[13];
    const float* sf_bi = (const float*)d_in[14];
    const float* sf_bh = (const float*)d_in[15];
    const float* sb_ih = (const float*)d_in[16];
    const float* sb_hh = (const float*)d_in[17];
    const float* sb_bi = (const float*)d_in[18];
    const float* sb_bh = (const float*)d_in[19];
    const float* doc_w  = (const float*)d_in[20];
    const float* doc_b  = (const float*)d_in[21];
    const float* sent_w = (const float*)d_in[22];
    const float* sent_b = (const float*)d_in[23];

    char* ws = (char*)d_ws;
    const size_t OFF_GX  = 0;                          // 8000*38*512 = 155,648,000
    const size_t OFF_SIN = 155648000;                  // 2560*416*4  =   4,259,840
    const size_t OFF_D   = OFF_SIN + 4259840;          // 256*400*4   =     409,600
    const size_t OFF_SL  = OFF_D + 409600;             // 2560*4
    const size_t OFF_BHH = OFF_SL + 10240;             // 4*40*7*1024 =   2,867,200
    const size_t OFF_BIW = OFF_BHH + 2867200;          // 2*40*10*2048=   1,638,400
    const size_t OFF_BIS = OFF_BIW + 1638400;          // 2*40*13*2048=   2,129,920
    bf16*  gx     = (bf16*)(ws + OFF_GX);
    float* s_in   = (float*)(ws + OFF_SIN);
    float* dpool  = (float*)(ws + OFF_D);
    int*   sl     = (int*)(ws + OFF_SL);
    bf16*  Bhh    = (bf16*)(ws + OFF_BHH);
    bf16*  BiW0   = (bf16*)(ws + OFF_BIW);
    bf16*  BiW1   = BiW0 + NTILES * KC_W * 2 * 64 * 8;
    bf16*  BiS0   = (bf16*)(ws + OFF_BIS);
    bf16*  BiS1   = BiS0 + NTILES * KC_S * 2 * 64 * 8;

    prepack_whh<<<(4 * NTILES * KCH * 64 + 255) / 256, 256, 0, stream>>>(
        wf_hh, wb_hh, sf_hh, sb_hh, Bhh);
    prepack_bih<<<(NTILES * KC_W * 64 + 255) / 256, 256, 0, stream>>>(wf_ih, BiW0, 300, KC_W);
    prepack_bih<<<(NTILES * KC_W * 64 + 255) / 256, 256, 0, stream>>>(wb_ih, BiW1, 300, KC_W);
    prepack_bih<<<(NTILES * KC_S * 64 + 255) / 256, 256, 0, stream>>>(sf_ih, BiS0, 400, KC_S);
    prepack_bih<<<(NTILES * KC_S * 64 + 255) / 256, 256, 0, stream>>>(sb_ih, BiS1, 400, KC_S);
    lens_kernel<<<(NS + 255) / 256, 256, 0, stream>>>(x, sl);
    zero_u32<<<(NS * SSTR + 255) / 256, 256, 0, stream>>>((unsigned*)s_in, NS * SSTR);

    // word level, forward
    gemm_mfma<true><<<dim3(1000, 5), 256, 0, stream>>>(emb, nullptr, 0, x, BiW0, KC_W, gx);
    gru_mfma<<<NS / 16, 512, 0, stream>>>(gx, Bhh, 0, wf_bh, wf_bi, sl, s_in, SSTR, TW, 0, 0);
    // word level, backward
    gemm_mfma<true><<<dim3(1000, 5), 256, 0, stream>>>(emb, nullptr, 0, x, BiW1, KC_W, gx);
    gru_mfma<<<NS / 16, 512, 0, stream>>>(gx, Bhh, NTILES, wb_bh, wb_bi, sl, s_in, SSTR, TW, HDIM, 1);
    // sentence level, forward
    gemm_mfma<false><<<dim3(20, 5), 256, 0, stream>>>(nullptr, s_in, SSTR, nullptr, BiS0, KC_S, gx);
    gru_mfma<<<ND / 16, 512, 0, stream>>>(gx, Bhh, 2 * NTILES, sf_bh, sf_bi, doc_lens, dpool, 400, DTR, 0, 0);
    // sentence level, backward
    gemm_mfma<false><<<dim3(20, 5), 256, 0, stream>>>(nullptr, s_in, SSTR, nullptr, BiS1, KC_S, gx);
    gru_mfma<<<ND / 16, 512, 0, stream>>>(gx, Bhh, 3 * NTILES, sb_bh, sb_bi, doc_lens, dpool, 400, DTR, HDIM, 1);

    head_kernel<<<1, 256, 0, stream>>>(dpool, doc_lens, doc_w, doc_b, sent_w, sent_b, (float*)d_out);
}

// Round 6
// 1101.631 us; speedup vs baseline: 4.2000x; 1.7919x over previous
//
#include <hip/hip_runtime.h>
#include <hip/hip_bf16.h>

// Hierarchical BiGRU. Round 6: per-gate tile padding (200->208, 13 tiles/gate,
// N=624) makes r/z/n for unit i share (lane,reg) across 3 tiles:
//  - gru_mfma: 13 waves (832 thr), wave w owns within-gate tile j=w for ALL
//    3 gates -> gate combine fully in registers (no ghs LDS), gx read as
//    coalesced dwordx2 in fragment layout, h hi/lo double-buffered in LDS,
//    ONE barrier per step. B-frags streamed from hot L2 (273 KB/dir).
//  - gemm_mfma: rows transposed row'=t*S+s so each gru (block,step) maps to
//    one 16-row fragment group; A hi/lo split (compensated), B single bf16
//    (2-pass, round-1-proven numerics); register prefetch of next A chunk.
// ws ~167 MB.

typedef __hip_bfloat16 bf16;
typedef short s16x8 __attribute__((ext_vector_type(8)));
typedef float f32x4 __attribute__((ext_vector_type(4)));

#define HDIM 200
#define G3   600
#define NS   2560
#define TW   50
#define ND   256
#define DTR  10

#define GT   13          // tiles per gate (208 cols)
#define NT   39          // stored tiles (3 gates x 13)
#define NTP  40          // packed-B tiles for gemm (last = zero pad)
#define KCH  7           // W_hh k-chunks (200 -> 224)
#define HSTR 232         // h LDS row stride (shorts)
#define KC_W 10          // word x-proj k-chunks (300 -> 320)
#define KC_S 13          // sent x-proj k-chunks (400 -> 416)
#define EMB_ELEMS 15000000
#define MTB  (NT*512)    // bytes per 16-row fragment group

__device__ __forceinline__ float sigf(float x) { return 1.f / (1.f + __expf(-x)); }
__device__ __forceinline__ float tanh_fast(float x) {
    float e = __expf(2.f * x);
    return (e - 1.f) / (e + 1.f);
}
__device__ __forceinline__ unsigned short f2bf(float f) {
    unsigned u = __float_as_uint(f);
    unsigned r = (u + 0x7FFFu + ((u >> 16) & 1u)) >> 16;
    return (unsigned short)r;
}
__device__ __forceinline__ float bf2f(unsigned short b) {
    return __uint_as_float(((unsigned)b) << 16);
}
__device__ __forceinline__ unsigned pk_bf(float a, float b) {
    unsigned ua = __float_as_uint(a) + 0x8000u;
    unsigned ub = __float_as_uint(b) + 0x8000u;
    return __builtin_amdgcn_perm(ub, ua, 0x07060302);
}
__device__ __forceinline__ void split2(float a, float b, unsigned& hi, unsigned& lo) {
    unsigned ua = __float_as_uint(a) + 0x8000u;
    unsigned ub = __float_as_uint(b) + 0x8000u;
    hi = __builtin_amdgcn_perm(ub, ua, 0x07060302);
    float ha = __uint_as_float(ua & 0xFFFF0000u);
    float hb = __uint_as_float(ub & 0xFFFF0000u);
    lo = pk_bf(a - ha, b - hb);
}
// select bf16 #rg (0..3) from a uint2 packed as (rg0,rg1 | rg2,rg3)
__device__ __forceinline__ float bfsel(uint2 v, int rg) {
    unsigned u = (rg & 2) ? v.y : v.x;
    return bf2f((unsigned short)((rg & 1) ? (u >> 16) : (u & 0xFFFFu)));
}

// ---------------- sentence lengths ----------------
__global__ void lens_kernel(const int* __restrict__ x, int* __restrict__ sl) {
    int s = blockIdx.x * 256 + threadIdx.x;
    if (s < NS) {
        int c = 0;
        for (int t = 0; t < TW; ++t) c += (x[s * TW + t] != 0) ? 1 : 0;
        sl[s] = c;
    }
}

// ------------- pre-pack W_hh into per-gate-padded MFMA B-fragments --------
// tile tIdx = g*13+j; B[k][n_local=j*16+c] = W[g*200 + j*16+c][k]; zero pads.
__global__ void prepack_whh(const float* __restrict__ w0, const float* __restrict__ w1,
                            const float* __restrict__ w2, const float* __restrict__ w3,
                            bf16* __restrict__ Bp) {
    int gid = blockIdx.x * 256 + threadIdx.x;
    if (gid >= 4 * NT * KCH * 64) return;
    int lane = gid & 63;
    int f = gid >> 6;
    int kc = f % KCH;
    int tIdx = (f / KCH) % NT;
    int d = f / (KCH * NT);
    const float* w = (d == 0) ? w0 : (d == 1) ? w1 : (d == 2) ? w2 : w3;
    int g = tIdx / GT, j = tIdx % GT;
    int il = j * 16 + (lane & 15);
    int n = g * HDIM + il;
    int kb = kc * 32 + (lane >> 4) * 8;
    unsigned short vals[8] __attribute__((aligned(16)));
#pragma unroll
    for (int jj = 0; jj < 8; ++jj) {
        int k = kb + jj;
        float v = (il < HDIM && k < HDIM) ? w[n * HDIM + k] : 0.f;
        vals[jj] = f2bf(v);
    }
    *reinterpret_cast<float4*>(reinterpret_cast<char*>(Bp) + (size_t)gid * 16) =
        *reinterpret_cast<const float4*>(vals);
}

// ------------- pre-pack W_ih into per-gate-padded B-fragments (single bf16)
__global__ void prepack_bih(const float* __restrict__ w, bf16* __restrict__ Bp,
                            int Kin, int KC) {
    int gid = blockIdx.x * 256 + threadIdx.x;
    if (gid >= NTP * KC * 64) return;
    int lane = gid & 63;
    int f = gid >> 6;
    int kc = f % KC;
    int tIdx = f / KC;
    int g = tIdx / GT, j = tIdx % GT;
    int il = j * 16 + (lane & 15);
    int n = g * HDIM + il;
    int kb = kc * 32 + (lane >> 4) * 8;
    unsigned short vals[8] __attribute__((aligned(16)));
#pragma unroll
    for (int jj = 0; jj < 8; ++jj) {
        int k = kb + jj;
        float v = (tIdx < NT && il < HDIM && k < Kin) ? w[n * Kin + k] : 0.f;
        vals[jj] = f2bf(v);
    }
    *reinterpret_cast<float4*>(reinterpret_cast<char*>(Bp) + (size_t)gid * 16) =
        *reinterpret_cast<const float4*>(vals);
}

// ---------------- MFMA GEMM (A compensated, B single): gx_frag = A @ B -----
// Row order TRANSPOSED: row' = t*S + s. GATHER: tok = idx[(row'%S)*Tseq + row'/S],
// A row = emb[tok] (f32). else: A = Afl[row'] (f32, astride elems).
// Output bf16 fragment layout: byte = ((gmt*39 + gnt)*64 + lane)*8 + reg*2.
template<bool GATHER>
__global__ __launch_bounds__(256) void gemm_mfma(
    const float* __restrict__ Aemb, const float* __restrict__ Afl, int astride,
    const int* __restrict__ idx, int S, int Tseq,
    const bf16* __restrict__ Bp, int KC, bf16* __restrict__ gxOut)
{
    __shared__ __align__(16) unsigned short Ahi[128 * 32];
    __shared__ __align__(16) unsigned short Alo[128 * 32];
    __shared__ int toks[128];

    const int tid = threadIdx.x;
    const int wv = tid >> 6, lane = tid & 63;
    const int bm = blockIdx.x, bn = blockIdx.y;

    if (GATHER && tid < 128) {
        int rp = bm * 128 + tid;
        toks[tid] = idx[(rp % S) * Tseq + (rp / S)];
    }

    int aaddr[4];
#pragma unroll
    for (int mt = 0; mt < 4; ++mt) {
        int row = (wv & 1) * 64 + mt * 16 + (lane & 15);
        aaddr[mt] = row * 32 + (((lane >> 4) ^ ((row >> 1) & 3)) << 3);
    }

    const int srow = tid >> 1, kh = tid & 1;
    const int ssw = (srow >> 1) & 3;

    f32x4 acc[4][4];
#pragma unroll
    for (int i = 0; i < 4; ++i)
#pragma unroll
        for (int j = 0; j < 4; ++j) acc[i][j] = (f32x4){0.f, 0.f, 0.f, 0.f};

    const uint4* bq = reinterpret_cast<const uint4*>(Bp);
    int gnt[4];
#pragma unroll
    for (int j = 0; j < 4; ++j) gnt[j] = bn * 8 + (wv >> 1) * 4 + j;

    __syncthreads();  // toks visible
    const int obase = GATHER ? (toks[srow] * 300 + kh * 16) : 0;
    const float* arow = GATHER ? nullptr
        : Afl + (size_t)(bm * 128 + srow) * astride + kh * 16;

    float4 f[4], fn[4];
    // preload kc=0
    if (GATHER) {
#pragma unroll
        for (int j = 0; j < 4; ++j) {
            int o = obase + j * 4;
            o = (o > EMB_ELEMS - 4) ? (EMB_ELEMS - 4) : o;
            f[j] = *reinterpret_cast<const float4*>(Aemb + o);
        }
    } else {
#pragma unroll
        for (int j = 0; j < 4; ++j)
            f[j] = *reinterpret_cast<const float4*>(arow + j * 4);
    }

    for (int kc = 0; kc < KC; ++kc) {
        if (kc) __syncthreads();  // prior iter's ds_reads done
#pragma unroll
        for (int g = 0; g < 2; ++g) {
            uint4 vh, vl;
            split2(f[g * 2].x, f[g * 2].y, vh.x, vl.x);
            split2(f[g * 2].z, f[g * 2].w, vh.y, vl.y);
            split2(f[g * 2 + 1].x, f[g * 2 + 1].y, vh.z, vl.z);
            split2(f[g * 2 + 1].z, f[g * 2 + 1].w, vh.w, vl.w);
            int slot = (kh * 2 + g) ^ ssw;
            *reinterpret_cast<uint4*>(&Ahi[srow * 32 + slot * 8]) = vh;
            *reinterpret_cast<uint4*>(&Alo[srow * 32 + slot * 8]) = vl;
        }
        __syncthreads();

        // prefetch next A chunk (overlaps MFMA below)
        if (kc + 1 < KC) {
            if (GATHER) {
                int ob = obase + (kc + 1) * 32;
#pragma unroll
                for (int j = 0; j < 4; ++j) {
                    int o = ob + j * 4;
                    o = (o > EMB_ELEMS - 4) ? (EMB_ELEMS - 4) : o;
                    fn[j] = *reinterpret_cast<const float4*>(Aemb + o);
                }
            } else {
#pragma unroll
                for (int j = 0; j < 4; ++j)
                    fn[j] = *reinterpret_cast<const float4*>(arow + (kc + 1) * 32 + j * 4);
            }
        }

        uint4 b[4];
#pragma unroll
        for (int j = 0; j < 4; ++j)
            b[j] = bq[(size_t)(gnt[j] * KC + kc) * 64 + lane];

        s16x8 ah[4], al[4];
#pragma unroll
        for (int mt = 0; mt < 4; ++mt) {
            ah[mt] = *reinterpret_cast<const s16x8*>(&Ahi[aaddr[mt]]);
            al[mt] = *reinterpret_cast<const s16x8*>(&Alo[aaddr[mt]]);
        }
#pragma unroll
        for (int mt = 0; mt < 4; ++mt)
#pragma unroll
            for (int j = 0; j < 4; ++j) {
                acc[mt][j] = __builtin_amdgcn_mfma_f32_16x16x32_bf16(
                    ah[mt], *reinterpret_cast<const s16x8*>(&b[j]), acc[mt][j], 0, 0, 0);
                acc[mt][j] = __builtin_amdgcn_mfma_f32_16x16x32_bf16(
                    al[mt], *reinterpret_cast<const s16x8*>(&b[j]), acc[mt][j], 0, 0, 0);
            }
        if (kc + 1 < KC) {
#pragma unroll
            for (int j = 0; j < 4; ++j) f[j] = fn[j];
        }
    }

#pragma unroll
    for (int mt = 0; mt < 4; ++mt) {
        int gmt = bm * 8 + (wv & 1) * 4 + mt;
#pragma unroll
        for (int j = 0; j < 4; ++j) {
            if (gnt[j] < NT) {
                uint2 v;
                v.x = pk_bf(acc[mt][j][0], acc[mt][j][1]);
                v.y = pk_bf(acc[mt][j][2], acc[mt][j][3]);
                *reinterpret_cast<uint2*>(reinterpret_cast<char*>(gxOut) +
                    ((size_t)(gmt * NT + gnt[j]) * 64 + lane) * 8) = v;
            }
        }
    }
}

// ---------------- MFMA GRU: in-register gate combine, 1 barrier/step -------
// 832 threads = 13 waves; wave w owns within-gate tile j=w for all 3 gates.
// Thread (w, lane): rows r = quad*4+rg (rg 0..3), unit i = w*16 + (lane&15).
// h (hi+lo bf16) double-buffered in LDS; B-frags streamed from L2 per step.
// poolMode 1: word level -> s_in row (sg%10)*ND + sg/10 (transposed for the
// sentence GEMM); poolMode 0: direct row (doc pool).
__global__ __launch_bounds__(832) void gru_mfma(
    const bf16* __restrict__ gx, const bf16* __restrict__ Bp, int dirBase,
    const float* __restrict__ bh, const float* __restrict__ bi,
    const int* __restrict__ lens, float* __restrict__ pool,
    int S, int T, int dirOff, int rev, int poolMode)
{
    __shared__ __align__(16) unsigned short hhi[2][16 * HSTR];
    __shared__ __align__(16) unsigned short hlo[2][16 * HSTR];

    const int tid = threadIdx.x;
    const int w = tid >> 6, lane = tid & 63;
    const int quad = lane >> 4, c = lane & 15;
    const int row0 = blockIdx.x * 16;
    const int i = w * 16 + c;
    const bool iv = (i < HDIM);

    for (int p = tid; p < 16 * HSTR; p += 832) {
        hhi[0][p] = 0; hhi[1][p] = 0; hlo[0][p] = 0; hlo[1][p] = 0;
    }

    float bhr = 0.f, bhz = 0.f, bhn = 0.f, binv = 0.f;
    if (iv) {
        bhr = bh[i] + bi[i];
        bhz = bh[HDIM + i] + bi[HDIM + i];
        bhn = bh[2 * HDIM + i];
        binv = bi[2 * HDIM + i];
    }
    int slenr[4];
    float hreg[4], pacc[4];
#pragma unroll
    for (int rg = 0; rg < 4; ++rg) {
        int L = lens[row0 + quad * 4 + rg];
        if (L < 0) L = 0;
        if (L > T) L = T;
        slenr[rg] = L;
        hreg[rg] = 0.f; pacc[rg] = 0.f;
    }

    const uint4* bq = reinterpret_cast<const uint4*>(Bp);
    size_t bo[3];
#pragma unroll
    for (int g = 0; g < 3; ++g)
        bo[g] = (size_t)(dirBase + g * GT + w) * KCH * 64 + lane;

    const char* gxb = reinterpret_cast<const char*>(gx);
    const int am = c * HSTR + quad * 8;
    const int SG = S / 16;
    const int hw0 = (quad * 4) * HSTR + i;

    __syncthreads();

    for (int ts = 0; ts < T; ++ts) {
        const int t = rev ? (T - 1 - ts) : ts;
        const int cur = ts & 1, nxt = cur ^ 1;
        const long long gg = (long long)t * SG + blockIdx.x;

        uint2 gxv[3];
#pragma unroll
        for (int g = 0; g < 3; ++g)
            gxv[g] = *reinterpret_cast<const uint2*>(
                gxb + ((gg * NT + g * GT + w) * 64 + lane) * 8);

        f32x4 a0 = (f32x4){0.f,0.f,0.f,0.f}, a1 = a0, a2 = a0;
#pragma unroll
        for (int kc = 0; kc < KCH; ++kc) {
            uint4 b0 = bq[bo[0] + kc * 64];
            uint4 b1 = bq[bo[1] + kc * 64];
            uint4 b2 = bq[bo[2] + kc * 64];
            s16x8 ah = *reinterpret_cast<const s16x8*>(&hhi[cur][am + kc * 32]);
            s16x8 al = *reinterpret_cast<const s16x8*>(&hlo[cur][am + kc * 32]);
            a0 = __builtin_amdgcn_mfma_f32_16x16x32_bf16(ah, *reinterpret_cast<const s16x8*>(&b0), a0, 0, 0, 0);
            a1 = __builtin_amdgcn_mfma_f32_16x16x32_bf16(ah, *reinterpret_cast<const s16x8*>(&b1), a1, 0, 0, 0);
            a2 = __builtin_amdgcn_mfma_f32_16x16x32_bf16(ah, *reinterpret_cast<const s16x8*>(&b2), a2, 0, 0, 0);
            a0 = __builtin_amdgcn_mfma_f32_16x16x32_bf16(al, *reinterpret_cast<const s16x8*>(&b0), a0, 0, 0, 0);
            a1 = __builtin_amdgcn_mfma_f32_16x16x32_bf16(al, *reinterpret_cast<const s16x8*>(&b1), a1, 0, 0, 0);
            a2 = __builtin_amdgcn_mfma_f32_16x16x32_bf16(al, *reinterpret_cast<const s16x8*>(&b2), a2, 0, 0, 0);
        }

        if (iv) {
#pragma unroll
            for (int rg = 0; rg < 4; ++rg) {
                float xr = bfsel(gxv[0], rg);
                float xz = bfsel(gxv[1], rg);
                float xn = bfsel(gxv[2], rg);
                float r = sigf(xr + a0[rg] + bhr);
                float z = sigf(xz + a1[rg] + bhz);
                float n = tanh_fast((xn + binv) + r * (a2[rg] + bhn));
                float hnew = (1.f - z) * n + z * hreg[rg];
                hreg[rg] = hnew;
                unsigned short hi = f2bf(hnew);
                hhi[nxt][hw0 + rg * HSTR] = hi;
                hlo[nxt][hw0 + rg * HSTR] = f2bf(hnew - bf2f(hi));
                if (t < slenr[rg]) pacc[rg] += hnew;
            }
        }
        __syncthreads();
    }

    if (iv) {
#pragma unroll
        for (int rg = 0; rg < 4; ++rg) {
            int sg = row0 + quad * 4 + rg;
            int L = slenr[rg];
            float v = (L > 0) ? pacc[rg] / (float)L : 0.f;
            int prow = poolMode ? ((sg % 10) * ND + sg / 10) : sg;
            pool[(size_t)prow * 400 + dirOff + i] = v;
        }
    }
}

// ---------------- heads ----------------
__global__ __launch_bounds__(256) void head_kernel(
    const float* __restrict__ d_pool, const int* __restrict__ doc_lens,
    const float* __restrict__ doc_w, const float* __restrict__ doc_b,
    const float* __restrict__ sent_w, const float* __restrict__ sent_b,
    float* __restrict__ out)
{
    __shared__ int sdl[ND];
    __shared__ int soff[ND + 1];
    const int tid = threadIdx.x;
    int dl = doc_lens[tid];
    if (dl < 0) dl = 0;
    if (dl > DTR) dl = DTR;
    sdl[tid] = dl;
    __syncthreads();
    if (tid == 0) {
        int run = 0;
        for (int i = 0; i < ND; ++i) { soff[i] = run; run += sdl[i]; }
        soff[ND] = run;
    }
    __syncthreads();

    const float* dv = d_pool + (size_t)tid * 400;
    float dp = doc_b[0];
    for (int f = 0; f < 400; ++f) dp += dv[f] * doc_w[f];
    out[tid] = sigf(dp);

    int base = ND + soff[tid];
    for (int c = 0; c < dl; ++c) {
        float sp = sent_b[c];
        const float* swr = sent_w + c * 400;
        for (int f = 0; f < 400; ++f) sp += dv[f] * swr[f];
        out[base + c] = sigf(sp);
    }
}

// --------------------------------------------------------------------------
extern "C" void kernel_launch(void* const* d_in, const int* in_sizes, int n_in,
                              void* d_out, int out_size, void* d_ws, size_t ws_size,
                              hipStream_t stream) {
    const int*   x        = (const int*)d_in[0];
    const int*   doc_lens = (const int*)d_in[2];
    const float* emb      = (const float*)d_in[3];
    const float* wf_ih = (const float*)d_in[4];
    const float* wf_hh = (const float*)d_in[5];
    const float* wf_bi = (const float*)d_in[6];
    const float* wf_bh = (const float*)d_in[7];
    const float* wb_ih = (const float*)d_in[8];
    const float* wb_hh = (const float*)d_in[9];
    const float* wb_bi = (const float*)d_in[10];
    const float* wb_bh = (const float*)d_in[11];
    const float* sf_ih = (const float*)d_in[12];
    const float* sf_hh = (const float*)d_in[13];
    const float* sf_bi = (const float*)d_in[14];
    const float* sf_bh = (const float*)d_in[15];
    const float* sb_ih = (const float*)d_in[16];
    const float* sb_hh = (const float*)d_in[17];
    const float* sb_bi = (const float*)d_in[18];
    const float* sb_bh = (const float*)d_in[19];
    const float* doc_w  = (const float*)d_in[20];
    const float* doc_b  = (const float*)d_in[21];
    const float* sent_w = (const float*)d_in[22];
    const float* sent_b = (const float*)d_in[23];

    char* ws = (char*)d_ws;
    const size_t OFF_GX  = 0;                        // 8000*39*512 = 159,744,000
    const size_t OFF_SIN = 159744000;                // 2560*400*4 + 64pad
    const size_t OFF_D   = OFF_SIN + 4096256;        // 256*400*4
    const size_t OFF_SL  = OFF_D + 409600;           // 2560*4
    const size_t OFF_BHH = OFF_SL + 10240;           // 4*39*7*1024 = 1,118,208
    const size_t OFF_BIW = OFF_BHH + 1118208;        // 2*40*10*1024 = 819,200
    const size_t OFF_BIS = OFF_BIW + 819200;         // 2*40*13*1024 = 1,064,960
    bf16*  gx     = (bf16*)(ws + OFF_GX);
    float* s_in   = (float*)(ws + OFF_SIN);
    float* dpool  = (float*)(ws + OFF_D);
    int*   sl     = (int*)(ws + OFF_SL);
    bf16*  Bhh    = (bf16*)(ws + OFF_BHH);
    bf16*  BiW0   = (bf16*)(ws + OFF_BIW);
    bf16*  BiW1   = BiW0 + NTP * KC_W * 64 * 8;
    bf16*  BiS0   = (bf16*)(ws + OFF_BIS);
    bf16*  BiS1   = BiS0 + NTP * KC_S * 64 * 8;

    prepack_whh<<<(4 * NT * KCH * 64 + 255) / 256, 256, 0, stream>>>(
        wf_hh, wb_hh, sf_hh, sb_hh, Bhh);
    prepack_bih<<<(NTP * KC_W * 64 + 255) / 256, 256, 0, stream>>>(wf_ih, BiW0, 300, KC_W);
    prepack_bih<<<(NTP * KC_W * 64 + 255) / 256, 256, 0, stream>>>(wb_ih, BiW1, 300, KC_W);
    prepack_bih<<<(NTP * KC_S * 64 + 255) / 256, 256, 0, stream>>>(sf_ih, BiS0, 400, KC_S);
    prepack_bih<<<(NTP * KC_S * 64 + 255) / 256, 256, 0, stream>>>(sb_ih, BiS1, 400, KC_S);
    lens_kernel<<<(NS + 255) / 256, 256, 0, stream>>>(x, sl);

    // word level, forward
    gemm_mfma<true><<<dim3(1000, 5), 256, 0, stream>>>(emb, nullptr, 0, x, NS, TW, BiW0, KC_W, gx);
    gru_mfma<<<NS / 16, 832, 0, stream>>>(gx, Bhh, 0 * NT, wf_bh, wf_bi, sl, s_in, NS, TW, 0, 0, 1);
    // word level, backward
    gemm_mfma<true><<<dim3(1000, 5), 256, 0, stream>>>(emb, nullptr, 0, x, NS, TW, BiW1, KC_W, gx);
    gru_mfma<<<NS / 16, 832, 0, stream>>>(gx, Bhh, 1 * NT, wb_bh, wb_bi, sl, s_in, NS, TW, HDIM, 1, 1);
    // sentence level, forward (A = s_in, rows already transposed slot*256+d)
    gemm_mfma<false><<<dim3(20, 5), 256, 0, stream>>>(nullptr, s_in, 400, nullptr, ND, DTR, BiS0, KC_S, gx);
    gru_mfma<<<ND / 16, 832, 0, stream>>>(gx, Bhh, 2 * NT, sf_bh, sf_bi, doc_lens, dpool, ND, DTR, 0, 0, 0);
    // sentence level, backward
    gemm_mfma<false><<<dim3(20, 5), 256, 0, stream>>>(nullptr, s_in, 400, nullptr, ND, DTR, BiS1, KC_S, gx);
    gru_mfma<<<ND / 16, 832, 0, stream>>>(gx, Bhh, 3 * NT, sb_bh, sb_bi, doc_lens, dpool, ND, DTR, HDIM, 1, 0);

    head_kernel<<<1, 256, 0, stream>>>(dpool, doc_lens, doc_w, doc_b, sent_w, sent_b, (float*)d_out);
}